// Round 7
// baseline (354.510 us; speedup 1.0000x reference)
//
#include <hip/hip_runtime.h>
#include <hip/hip_bf16.h>
#include <cstdint>
#include <cstddef>

// Problem constants (fixed by the reference)
#define BATCH 128
#define SEQ   512
#define DIM   1024
#define MROWS (BATCH * SEQ)          // 65536
#define NT    32                     // K sub-tiles of 32 (DIM/32)

typedef short short8 __attribute__((ext_vector_type(8)));
typedef __bf16 bf16x8 __attribute__((ext_vector_type(8)));
typedef float f32x4 __attribute__((ext_vector_type(4)));
typedef float f32x16 __attribute__((ext_vector_type(16)));

// ---------- MFMA wrapper: accept either builtin signature (short8 or bf16x8) ----------
template <typename VA> struct other_frag { using type = bf16x8; };
template <> struct other_frag<bf16x8> { using type = short8; };

template <typename VA>
__device__ __forceinline__ auto try_mfma32(VA a, VA b, f32x16 c, int)
    -> decltype(__builtin_amdgcn_mfma_f32_32x32x16_bf16(a, b, c, 0, 0, 0)) {
  return __builtin_amdgcn_mfma_f32_32x32x16_bf16(a, b, c, 0, 0, 0);
}
template <typename VA>
__device__ __forceinline__ f32x16 try_mfma32(VA a, VA b, f32x16 c, long) {
  using O = typename other_frag<VA>::type;
  O a2 = __builtin_bit_cast(O, a);
  O b2 = __builtin_bit_cast(O, b);
  return __builtin_amdgcn_mfma_f32_32x32x16_bf16(a2, b2, c, 0, 0, 0);
}
__device__ __forceinline__ f32x16 mfma32_bf16(short8 a, short8 b, f32x16 c) {
  return try_mfma32(a, b, c, 0);
}

// ---------- helpers ----------
__device__ __forceinline__ unsigned short f32_to_bf16(float f) {
  union { float f; uint32_t u; } v; v.f = f;
  uint32_t u = v.u;
  u += 0x7FFFu + ((u >> 16) & 1u);   // round-to-nearest-even
  return (unsigned short)(u >> 16);
}

__device__ __forceinline__ float bf16_to_f32(unsigned short u) {
  union { uint32_t u; float f; } v; v.u = ((uint32_t)u) << 16; return v.f;
}

__device__ __forceinline__ void gload_lds16(const void* g, void* l) {
  __builtin_amdgcn_global_load_lds(
      (__attribute__((address_space(1))) void*)g,
      (__attribute__((address_space(3))) void*)l,
      16, 0, 0);
}

__device__ __forceinline__ float fast_tanh(float x) {
  x = fminf(fmaxf(x, -15.0f), 15.0f);
  float e = __expf(2.0f * x);
  return (e - 1.0f) / (e + 1.0f);
}

// ---------- kernel 1: cast X fp32 -> bf16, with fused u_last copy ----------
__global__ __launch_bounds__(256) void cast_x_kernel(const float* __restrict__ X,
                                                     unsigned short* __restrict__ Xb,
                                                     float* __restrict__ u_last) {
  const int total8 = MROWS * DIM / 8;        // 8388608 groups of 8
  int idx = blockIdx.x * 256 + threadIdx.x;
  const int stride = 2048 * 256;
  for (int i = idx; i < total8; i += stride) {
    const f32x4* p = (const f32x4*)X + (size_t)i * 2;
    f32x4 a = p[0];
    f32x4 b = p[1];
    short8 o;
    o[0] = (short)f32_to_bf16(a[0]); o[1] = (short)f32_to_bf16(a[1]);
    o[2] = (short)f32_to_bf16(a[2]); o[3] = (short)f32_to_bf16(a[3]);
    o[4] = (short)f32_to_bf16(b[0]); o[5] = (short)f32_to_bf16(b[1]);
    o[6] = (short)f32_to_bf16(b[2]); o[7] = (short)f32_to_bf16(b[3]);
    *((short8*)Xb + i) = o;
    int row = i >> 7;                 // global m-row of this 8-group
    if ((row & (SEQ - 1)) == SEQ - 1) {
      // u_last[b][g*8 .. g*8+8) = X[b][511][...]  (exact fp32 copy)
      int g = i & 127;
      f32x4* dst = (f32x4*)(u_last + (size_t)(row >> 9) * DIM + g * 8);
      dst[0] = a;
      dst[1] = b;
    }
  }
}

// ---------- kernel 2: W1 (D x D) -> W1t bf16 (transposed, [e][d]) ----------
__global__ __launch_bounds__(256) void w1t_kernel(const float* __restrict__ W1,
                                                  unsigned short* __restrict__ W1t) {
  __shared__ float tile[64][65];
  int bx = blockIdx.x & 15;    // e-tile
  int by = blockIdx.x >> 4;    // d-tile
  int t = threadIdx.x;
  int c = t & 63, r0 = t >> 6;
#pragma unroll
  for (int i = 0; i < 16; i++) {
    int r = i * 4 + r0;
    tile[r][c] = W1[(size_t)(by * 64 + r) * DIM + bx * 64 + c];
  }
  __syncthreads();
#pragma unroll
  for (int i = 0; i < 16; i++) {
    int r = i * 4 + r0;
    W1t[(size_t)(bx * 64 + r) * DIM + by * 64 + c] = f32_to_bf16(tile[c][r]);
  }
}

// ---------- kernel 3: 256x256-tile pipelined GEMM (32x32x16 MFMA) ----------
// C[m][e] = sum_d Xb[m][d] * W1t[e][d];  scores[m] += sum_e tanh(C+b1[e]) * w2[e]
//
// R2 skeleton (measured 183 us, 0 bank conflicts, FETCH 98 MB), with the MFMA
// switched to 32x32x16 (ubench 2382 vs 2075 TF; 16 MFMA/K-step instead of 32,
// matrix-pipe cycles -17%).  8 waves (2M x 4N), per-wave output 128x64.
// K pipelined in sub-tiles of 32 with a depth-4 LDS ring (4 x (16KB A + 16KB
// B) = 128 KB).  One barrier + counted vmcnt(8) per sub-tile (tail 4 -> 0).
//
// LDS layout per 16KB buffer ([256 rows][32 k] bf16): row pairs packed into
// 128-B stored rows; 16-B chunk index within stored row = logical ^ (srow&7).
// 32-row frag reads keep the same 2-way-per-16-lane-group bank pattern as the
// measured-0 16-row reads (same XOR family, chunk = kk*2 + (lane>>5)).
// Staging writes LDS linearly (global_load_lds); the global source applies
// the inverse (same) permutation.
__global__ __launch_bounds__(512, 2) void gemm_score_kernel(
    const unsigned short* __restrict__ Xb,    // [MROWS][DIM]
    const unsigned short* __restrict__ W1t,   // [DIM][DIM]  (e-major)
    const float* __restrict__ b1,
    const float* __restrict__ w2,
    float* __restrict__ scores) {             // [MROWS]
  __shared__ __align__(16) char lds[131072];  // A: [0,64K), B: [64K,128K)

  const int tid = threadIdx.x;
  const int lane = tid & 63;
  const int w = tid >> 6;                     // wave 0..7
  const int wr = w >> 2, wc = w & 3;          // 2 x 4 wave grid

  // chunked XCD swizzle: 1024 blocks, 8 XCDs, n-fastest within each chunk
  const int bx = blockIdx.x;
  const int swz = (bx & 7) * 128 + (bx >> 3);
  const int m0 = (swz >> 2) * 256;
  const int n0 = (swz & 3) * 256;

  // ---- staging addresses.  chunk sc = (i*8+w)*64 + lane, LDS byte = sc*16.
  // inverse map: srow = sc>>3, ic = sc&7, j = ic ^ (srow&7),
  //              row = srow*2 + (j>>2), k16 = j&3.
  const unsigned short *a0Src, *a1Src, *b0Src, *b1Src;
  {
    int sc0 = w * 64 + lane;
    int sr0 = sc0 >> 3, j0 = (sc0 & 7) ^ (sr0 & 7);
    int row0 = sr0 * 2 + (j0 >> 2), c40 = j0 & 3;
    a0Src = Xb  + (size_t)(m0 + row0) * DIM + c40 * 8;
    b0Src = W1t + (size_t)(n0 + row0) * DIM + c40 * 8;
    int sc1 = (8 + w) * 64 + lane;
    int sr1 = sc1 >> 3, j1 = (sc1 & 7) ^ (sr1 & 7);
    int row1 = sr1 * 2 + (j1 >> 2), c41 = j1 & 3;
    a1Src = Xb  + (size_t)(m0 + row1) * DIM + c41 * 8;
    b1Src = W1t + (size_t)(n0 + row1) * DIM + c41 * 8;
  }
  const int dst0 = w * 1024;          // wave-uniform LDS dest base (bytes)
  const int dst1 = (8 + w) * 1024;

  // ---- fragment LDS byte offsets (within a buffer)
  // A frag (mi, kk): row = wr*128 + mi*32 + (lane&31), chunk = kk*2+(lane>>5)
  int aOff[4][2];
#pragma unroll
  for (int mi = 0; mi < 4; mi++) {
    int row = wr * 128 + mi * 32 + (lane & 31);
    int srow = row >> 1;
#pragma unroll
    for (int kk = 0; kk < 2; kk++) {
      int ic = ((row & 1) * 4 + kk * 2 + (lane >> 5)) ^ (srow & 7);
      aOff[mi][kk] = srow * 128 + ic * 16;
    }
  }
  // B frag (ni, kk): row = wc*64 + ni*32 + (lane&31)  (row = e index)
  int bOff[2][2];
#pragma unroll
  for (int ni = 0; ni < 2; ni++) {
    int row = wc * 64 + ni * 32 + (lane & 31);
    int srow = row >> 1;
#pragma unroll
    for (int kk = 0; kk < 2; kk++) {
      int ic = ((row & 1) * 4 + kk * 2 + (lane >> 5)) ^ (srow & 7);
      bOff[ni][kk] = 65536 + srow * 128 + ic * 16;
    }
  }

  f32x16 acc[4][2];
#pragma unroll
  for (int mi = 0; mi < 4; mi++)
#pragma unroll
    for (int ni = 0; ni < 2; ni++)
      acc[mi][ni] = (f32x16)(0.f);

  short8 af[4][2], bfv[2][2];

#define STAGE(S) do {                                                   \
    const int bufS_ = ((S) & 3) * 16384;                                \
    const int ktS_ = (S) * 32;                                          \
    gload_lds16(a0Src + ktS_, lds + bufS_ + dst0);                      \
    gload_lds16(a1Src + ktS_, lds + bufS_ + dst1);                      \
    gload_lds16(b0Src + ktS_, lds + 65536 + bufS_ + dst0);              \
    gload_lds16(b1Src + ktS_, lds + 65536 + bufS_ + dst1);              \
  } while (0)

#define KITER(S, VMSTR) do {                                            \
    asm volatile("s_waitcnt vmcnt(" VMSTR ")" ::: "memory");            \
    __builtin_amdgcn_s_barrier();                                       \
    __builtin_amdgcn_sched_barrier(0);                                  \
    if ((S) + 3 < NT) STAGE((S) + 3);                                   \
    const int buf_ = ((S) & 3) * 16384;                                 \
    _Pragma("unroll")                                                   \
    for (int mi = 0; mi < 4; mi++)                                      \
      _Pragma("unroll")                                                 \
      for (int kk = 0; kk < 2; kk++)                                    \
        af[mi][kk] = *(const short8*)(lds + buf_ + aOff[mi][kk]);       \
    _Pragma("unroll")                                                   \
    for (int ni = 0; ni < 2; ni++)                                      \
      _Pragma("unroll")                                                 \
      for (int kk = 0; kk < 2; kk++)                                    \
        bfv[ni][kk] = *(const short8*)(lds + buf_ + bOff[ni][kk]);      \
    __builtin_amdgcn_s_setprio(1);                                      \
    _Pragma("unroll")                                                   \
    for (int kk = 0; kk < 2; kk++)                                      \
      _Pragma("unroll")                                                 \
      for (int mi = 0; mi < 4; mi++)                                    \
        _Pragma("unroll")                                               \
        for (int ni = 0; ni < 2; ni++)                                  \
          acc[mi][ni] = mfma32_bf16(af[mi][kk], bfv[ni][kk], acc[mi][ni]); \
    __builtin_amdgcn_s_setprio(0);                                      \
  } while (0)

  // prologue: 3 sub-tiles in flight (12 wave-loads)
  STAGE(0); STAGE(1); STAGE(2);

  for (int s = 0; s < NT - 2; ++s) KITER(s, "8");
  KITER(NT - 2, "4");
  KITER(NT - 1, "0");

#undef STAGE
#undef KITER

  // epilogue: scores[row] += sum over this wave's 64 cols of tanh(c + b1) * w2
  // C/D layout (32x32): col = lane&31, row = (reg&3) + 8*(reg>>2) + 4*(lane>>5)
  const int colL = lane & 31;
  const int hi = lane >> 5;
#pragma unroll
  for (int mi = 0; mi < 4; mi++) {
    float p[16];
#pragma unroll
    for (int r = 0; r < 16; r++) p[r] = 0.f;
#pragma unroll
    for (int ni = 0; ni < 2; ni++) {
      int col = n0 + wc * 64 + ni * 32 + colL;
      float w2v = w2[col];
      float b1v = b1[col];
#pragma unroll
      for (int r = 0; r < 16; r++)
        p[r] += fast_tanh(acc[mi][ni][r] + b1v) * w2v;
    }
    // reduce across the 32-lane half (cols); offsets stay within the half
#pragma unroll
    for (int off = 1; off < 32; off <<= 1) {
#pragma unroll
      for (int r = 0; r < 16; r++)
        p[r] += __shfl_xor(p[r], off);
    }
    if (colL == 0) {
      int mbase = m0 + wr * 128 + mi * 32 + 4 * hi;
#pragma unroll
      for (int r = 0; r < 16; r++) {
        int row = mbase + (r & 3) + 8 * (r >> 2);
        atomicAdd(&scores[row], p[r]);
      }
    }
  }
}

// ---------- kernel 4: masked softmax + u_att (reads bf16 Xb) ----------
__global__ __launch_bounds__(256) void attn_uatt_kernel(
    const unsigned short* __restrict__ Xb,
    const float* __restrict__ scores,
    const int* __restrict__ mask,
    float* __restrict__ u_att) {
  const int b = blockIdx.x;
  const int half = blockIdx.y;            // d-range [half*512, half*512+512)
  const int tid = threadIdx.x;
  const int lane = tid & 63;
  const int wave = tid >> 6;

  __shared__ float attn[SEQ];
  __shared__ float rbuf[4];
  __shared__ float part[3][64 * 9];       // padded stride 9

  float s0 = scores[(size_t)b * SEQ + tid];
  float s1 = scores[(size_t)b * SEQ + 256 + tid];
  if (mask[(size_t)b * SEQ + tid]) s0 = -1000000000.0f;
  if (mask[(size_t)b * SEQ + 256 + tid]) s1 = -1000000000.0f;

  float mx = fmaxf(s0, s1);
#pragma unroll
  for (int off = 1; off < 64; off <<= 1) mx = fmaxf(mx, __shfl_xor(mx, off));
  if (lane == 0) rbuf[wave] = mx;
  __syncthreads();
  mx = fmaxf(fmaxf(rbuf[0], rbuf[1]), fmaxf(rbuf[2], rbuf[3]));

  float p0 = expf(s0 - mx), p1 = expf(s1 - mx);
  float sm = p0 + p1;
#pragma unroll
  for (int off = 1; off < 64; off <<= 1) sm += __shfl_xor(sm, off);
  __syncthreads();
  if (lane == 0) rbuf[wave] = sm;
  __syncthreads();
  sm = rbuf[0] + rbuf[1] + rbuf[2] + rbuf[3];
  float inv = 1.0f / sm;
  attn[tid] = p0 * inv;
  attn[tid + 256] = p1 * inv;
  __syncthreads();

  // u_att[b][d] = sum_s attn[s] * X[b][s][d]; block covers 512 d (64 chunks of 8)
  const int col = tid & 63;            // 8-bf16 chunk within the half
  const int sh = tid >> 6;             // s-range split: [sh*128, sh*128+128)
  const short8* Xp = (const short8*)Xb + (size_t)b * SEQ * (DIM / 8) + half * 64 + col;
  float a[8] = {0.f, 0.f, 0.f, 0.f, 0.f, 0.f, 0.f, 0.f};
  for (int s = sh * 128; s < sh * 128 + 128; s++) {
    short8 v = Xp[(size_t)s * (DIM / 8)];
    float wgt = attn[s];
#pragma unroll
    for (int j = 0; j < 8; j++)
      a[j] += wgt * bf16_to_f32((unsigned short)v[j]);
  }
  if (sh) {
#pragma unroll
    for (int j = 0; j < 8; j++) part[sh - 1][col * 9 + j] = a[j];
  }
  __syncthreads();
  if (sh == 0) {
#pragma unroll
    for (int j = 0; j < 8; j++)
      a[j] += part[0][col * 9 + j] + part[1][col * 9 + j] + part[2][col * 9 + j];
    f32x4 lo = {a[0], a[1], a[2], a[3]};
    f32x4 hi4 = {a[4], a[5], a[6], a[7]};
    f32x4* dst = (f32x4*)(u_att + (size_t)b * DIM + half * 512 + col * 8);
    dst[0] = lo;
    dst[1] = hi4;
  }
}

// ---------- launcher ----------
extern "C" void kernel_launch(void* const* d_in, const int* in_sizes, int n_in,
                              void* d_out, int out_size, void* d_ws, size_t ws_size,
                              hipStream_t stream) {
  const float* X    = (const float*)d_in[0];   // [128][512][1024] fp32
  const int*   mask = (const int*)d_in[1];     // [128][512] int32 (bool)
  const float* W1   = (const float*)d_in[2];   // [1024][1024]
  const float* b1   = (const float*)d_in[3];   // [1024]
  const float* w2   = (const float*)d_in[4];   // [1024]

  float* out    = (float*)d_out;
  float* u_last = out;                          // [128][1024]
  float* u_att  = out + BATCH * DIM;            // [128][1024]

  char* ws = (char*)d_ws;
  unsigned short* Xb  = (unsigned short*)ws;                                // 128 MB
  unsigned short* W1t = (unsigned short*)(ws + (size_t)MROWS * DIM * 2);    // 2 MB
  float* scores = (float*)(ws + (size_t)MROWS * DIM * 2 + (size_t)DIM * DIM * 2); // 256 KB

  hipMemsetAsync(scores, 0, MROWS * sizeof(float), stream);
  hipLaunchKernelGGL(cast_x_kernel, dim3(2048), dim3(256), 0, stream, X, Xb, u_last);
  hipLaunchKernelGGL(w1t_kernel, dim3(256), dim3(256), 0, stream, W1, W1t);
  hipLaunchKernelGGL(gemm_score_kernel, dim3(1024), dim3(512), 0, stream,
                     Xb, W1t, b1, w2, scores);
  hipLaunchKernelGGL(attn_uatt_kernel, dim3(128, 2), dim3(256), 0, stream,
                     Xb, scores, mask, u_att);
}

// Round 8
// 261.702 us; speedup vs baseline: 1.3546x; 1.3546x over previous
//
#include <hip/hip_runtime.h>
#include <hip/hip_bf16.h>
#include <cstdint>
#include <cstddef>

// Problem constants (fixed by the reference)
#define BATCH 128
#define SEQ   512
#define DIM   1024
#define MROWS (BATCH * SEQ)          // 65536
#define NT    32                     // K sub-tiles of 32 (DIM/32)

typedef short short8 __attribute__((ext_vector_type(8)));
typedef __bf16 bf16x8 __attribute__((ext_vector_type(8)));
typedef float f32x4 __attribute__((ext_vector_type(4)));

// ---------- MFMA wrapper: accept either builtin signature (short8 or bf16x8) ----------
template <typename VA> struct other_frag { using type = bf16x8; };
template <> struct other_frag<bf16x8> { using type = short8; };

template <typename VA>
__device__ __forceinline__ auto try_mfma(VA a, VA b, f32x4 c, int)
    -> decltype(__builtin_amdgcn_mfma_f32_16x16x32_bf16(a, b, c, 0, 0, 0)) {
  return __builtin_amdgcn_mfma_f32_16x16x32_bf16(a, b, c, 0, 0, 0);
}
template <typename VA>
__device__ __forceinline__ f32x4 try_mfma(VA a, VA b, f32x4 c, long) {
  using O = typename other_frag<VA>::type;
  O a2 = __builtin_bit_cast(O, a);
  O b2 = __builtin_bit_cast(O, b);
  return __builtin_amdgcn_mfma_f32_16x16x32_bf16(a2, b2, c, 0, 0, 0);
}
__device__ __forceinline__ f32x4 mfma_bf16(short8 a, short8 b, f32x4 c) {
  return try_mfma(a, b, c, 0);
}

// ---------- helpers ----------
__device__ __forceinline__ unsigned short f32_to_bf16(float f) {
  union { float f; uint32_t u; } v; v.f = f;
  uint32_t u = v.u;
  u += 0x7FFFu + ((u >> 16) & 1u);   // round-to-nearest-even
  return (unsigned short)(u >> 16);
}

// 8 x f32 -> 8 x bf16 (RNE)
__device__ __forceinline__ short8 cvt8(f32x4 a, f32x4 b) {
  bf16x8 o;
  o[0] = (__bf16)a[0]; o[1] = (__bf16)a[1]; o[2] = (__bf16)a[2]; o[3] = (__bf16)a[3];
  o[4] = (__bf16)b[0]; o[5] = (__bf16)b[1]; o[6] = (__bf16)b[2]; o[7] = (__bf16)b[3];
  return __builtin_bit_cast(short8, o);
}

__device__ __forceinline__ void gload_lds16(const void* g, void* l) {
  __builtin_amdgcn_global_load_lds(
      (__attribute__((address_space(1))) void*)g,
      (__attribute__((address_space(3))) void*)l,
      16, 0, 0);
}

__device__ __forceinline__ float fast_tanh(float x) {
  x = fminf(fmaxf(x, -15.0f), 15.0f);
  float e = __expf(2.0f * x);
  return (e - 1.0f) / (e + 1.0f);
}

// ---------- kernel 1: W1 (D x D) -> W1t bf16 (transposed, [e][d]) ----------
__global__ __launch_bounds__(256) void w1t_kernel(const float* __restrict__ W1,
                                                  unsigned short* __restrict__ W1t) {
  __shared__ float tile[64][65];
  int bx = blockIdx.x & 15;    // e-tile
  int by = blockIdx.x >> 4;    // d-tile
  int t = threadIdx.x;
  int c = t & 63, r0 = t >> 6;
#pragma unroll
  for (int i = 0; i < 16; i++) {
    int r = i * 4 + r0;
    tile[r][c] = W1[(size_t)(by * 64 + r) * DIM + bx * 64 + c];
  }
  __syncthreads();
#pragma unroll
  for (int i = 0; i < 16; i++) {
    int r = i * 4 + r0;
    W1t[(size_t)(bx * 64 + r) * DIM + by * 64 + c] = f32_to_bf16(tile[c][r]);
  }
}

// ---------- kernel 2: 256x256-tile pipelined GEMM (fp32 A direct) ----------
// C[m][e] = sum_d bf16(X[m][d]) * W1t[e][d]; scores[m] += sum_e tanh(C+b1[e])*w2[e]
//
// EXACT R2 skeleton (183 us measured, 0 conflicts): 8 waves (2M x 4N),
// per-wave output 128x64, one raw barrier + counted vmcnt per K32-subtile,
// 16-row fragments, XCD-chunked grid.  Only change: A is staged as FP32
// directly from X via global_load_lds (no cast kernel, no Xb).
//   A: ring-3 x 32 KB fp32  [0, 96K)     4 gloads/thread/subtile
//   B: ring-3 x 16 KB bf16  [96K, 144K)  2 gloads/thread/subtile
// vmcnt: 6 loads/thread/subtile, depth-2 in flight -> vmcnt(6) steady,
// vmcnt(0) at the last subtile.  Stage target slot (S+2)%3 == (S-1)%3 was
// fully consumed before this iteration's top barrier (reads feed MFMAs that
// issued before the barrier).
//
// LDS layouts (both give 2-way-per-16-lane-group bank pattern = free):
//  A fp32 [256 rows][32 k]: one row = 128-B stored row; 16-B chunk
//    js = j ^ (row&7), j = float-quad index 0..7.
//    frag read (row = base+(lane&15), j = (lane>>4)*2+c): lanes 0-15 hit each
//    bank-quad exactly 2x (same structure as the measured-0 bf16 scheme).
//  B bf16 [256 rows][32 k]: row-pairs in 128-B stored rows; chunk
//    js = ((row&1)*4 + k16) ^ (srow&7), srow = row>>1 (measured 0 conflicts).
// Staging writes LDS linearly (global_load_lds); global source applies the
// inverse permutation.
__global__ __launch_bounds__(512, 2) void gemm_score_kernel(
    const float* __restrict__ X,              // [MROWS][DIM] fp32
    const unsigned short* __restrict__ W1t,   // [DIM][DIM]  (e-major)
    const float* __restrict__ b1,
    const float* __restrict__ w2,
    float* __restrict__ scores) {             // [MROWS]
  __shared__ __align__(16) char lds[147456];  // A: [0,96K)  B: [96K,144K)

  const int tid = threadIdx.x;
  const int lane = tid & 63;
  const int w = tid >> 6;                     // wave 0..7
  const int wr = w >> 2, wc = w & 3;          // 2 x 4 wave grid

  // chunked XCD swizzle: 1024 blocks, 8 XCDs, n-fastest within each chunk
  const int bx = blockIdx.x;
  const int swz = (bx & 7) * 128 + (bx >> 3);
  const int m0 = (swz >> 2) * 256;
  const int n0 = (swz & 3) * 256;

  // ---- A staging sources: 4 chunks/thread, sc = i*512 + tid (16B fp32 chunks)
  // inverse: row = sc>>3, j = (sc&7) ^ (row&7), float off = j*4
  const float* aSrc[4];
#pragma unroll
  for (int i = 0; i < 4; i++) {
    int sc = i * 512 + tid;
    int row = sc >> 3;
    int j = (sc & 7) ^ (row & 7);
    aSrc[i] = X + (size_t)(m0 + row) * DIM + j * 4;
  }
  // ---- B staging sources: 2 chunks/thread, sc = i*512 + tid (16B bf16 chunks)
  const unsigned short* bSrc[2];
#pragma unroll
  for (int i = 0; i < 2; i++) {
    int sc = i * 512 + tid;
    int srow = sc >> 3;
    int j = (sc & 7) ^ (srow & 7);
    int row = srow * 2 + (j >> 2);
    bSrc[i] = W1t + (size_t)(n0 + row) * DIM + (j & 3) * 8;
  }

  // ---- fragment LDS byte offsets
  int aOff[8][2];                             // A: within a 32KB fp32 buffer
#pragma unroll
  for (int mi = 0; mi < 8; mi++) {
    int row = wr * 128 + mi * 16 + (lane & 15);
#pragma unroll
    for (int c = 0; c < 2; c++) {
      int j = ((lane >> 4) * 2 + c) ^ (row & 7);
      aOff[mi][c] = row * 128 + j * 16;
    }
  }
  int bOff[4];                                // B: within a 16KB bf16 buffer
#pragma unroll
  for (int ni = 0; ni < 4; ni++) {
    int row = wc * 64 + ni * 16 + (lane & 15);
    int srow = row >> 1;
    int ic = ((row & 1) * 4 + (lane >> 4)) ^ (srow & 7);
    bOff[ni] = srow * 128 + ic * 16;
  }

  f32x4 acc[8][4];
#pragma unroll
  for (int mi = 0; mi < 8; mi++)
#pragma unroll
    for (int ni = 0; ni < 4; ni++)
      acc[mi][ni] = (f32x4){0.f, 0.f, 0.f, 0.f};

  short8 af[8], bfv[4];

#define STAGE(S) do {                                                   \
    const int bufA_ = ((S) % 3) * 32768;                                \
    const int bufB_ = 98304 + ((S) % 3) * 16384;                        \
    const int koF_ = (S) * 32;                                          \
    gload_lds16(aSrc[0] + koF_, lds + bufA_ + w * 1024);                \
    gload_lds16(aSrc[1] + koF_, lds + bufA_ + 8192 + w * 1024);         \
    gload_lds16(aSrc[2] + koF_, lds + bufA_ + 16384 + w * 1024);        \
    gload_lds16(aSrc[3] + koF_, lds + bufA_ + 24576 + w * 1024);        \
    gload_lds16(bSrc[0] + koF_, lds + bufB_ + w * 1024);                \
    gload_lds16(bSrc[1] + koF_, lds + bufB_ + 8192 + w * 1024);         \
  } while (0)

#define KITER(S, VMSTR) do {                                            \
    asm volatile("s_waitcnt vmcnt(" VMSTR ")" ::: "memory");            \
    __builtin_amdgcn_s_barrier();                                       \
    __builtin_amdgcn_sched_barrier(0);                                  \
    if ((S) + 2 < NT) STAGE((S) + 2);                                   \
    const char* bufA_ = lds + ((S) % 3) * 32768;                        \
    const char* bufB_ = lds + 98304 + ((S) % 3) * 16384;                \
    _Pragma("unroll")                                                   \
    for (int mi = 0; mi < 8; mi++) {                                    \
      f32x4 lo_ = *(const f32x4*)(bufA_ + aOff[mi][0]);                 \
      f32x4 hi_ = *(const f32x4*)(bufA_ + aOff[mi][1]);                 \
      af[mi] = cvt8(lo_, hi_);                                          \
    }                                                                   \
    _Pragma("unroll")                                                   \
    for (int ni = 0; ni < 4; ni++)                                      \
      bfv[ni] = *(const short8*)(bufB_ + bOff[ni]);                     \
    __builtin_amdgcn_s_setprio(1);                                      \
    _Pragma("unroll")                                                   \
    for (int mi = 0; mi < 8; mi++)                                      \
      _Pragma("unroll")                                                 \
      for (int ni = 0; ni < 4; ni++)                                    \
        acc[mi][ni] = mfma_bf16(af[mi], bfv[ni], acc[mi][ni]);          \
    __builtin_amdgcn_s_setprio(0);                                      \
  } while (0)

  // prologue: 2 sub-tiles in flight (12 wave-loads)
  STAGE(0); STAGE(1);

  for (int s = 0; s < NT - 1; ++s) KITER(s, "6");
  KITER(NT - 1, "0");

#undef STAGE
#undef KITER

  // epilogue: scores[row] += sum over this wave's 64 cols of tanh(c + b1) * w2
  const int cg = lane >> 4;   // row group: rows cg*4 + j
  const int cl = lane & 15;   // col within fragment
#pragma unroll
  for (int mi = 0; mi < 8; mi++) {
    float p0 = 0.f, p1 = 0.f, p2 = 0.f, p3 = 0.f;
#pragma unroll
    for (int ni = 0; ni < 4; ni++) {
      int col = n0 + wc * 64 + ni * 16 + cl;
      float w2v = w2[col];
      float b1v = b1[col];
      p0 += fast_tanh(acc[mi][ni][0] + b1v) * w2v;
      p1 += fast_tanh(acc[mi][ni][1] + b1v) * w2v;
      p2 += fast_tanh(acc[mi][ni][2] + b1v) * w2v;
      p3 += fast_tanh(acc[mi][ni][3] + b1v) * w2v;
    }
#pragma unroll
    for (int off = 1; off < 16; off <<= 1) {
      p0 += __shfl_xor(p0, off);
      p1 += __shfl_xor(p1, off);
      p2 += __shfl_xor(p2, off);
      p3 += __shfl_xor(p3, off);
    }
    if (cl == 0) {
      int row = m0 + wr * 128 + mi * 16 + cg * 4;
      atomicAdd(&scores[row + 0], p0);
      atomicAdd(&scores[row + 1], p1);
      atomicAdd(&scores[row + 2], p2);
      atomicAdd(&scores[row + 3], p3);
    }
  }
}

// ---------- kernel 3: masked softmax + u_att + u_last (fp32 X) ----------
__global__ __launch_bounds__(256) void attn_uatt_kernel(
    const float* __restrict__ X,
    const float* __restrict__ scores,
    const int* __restrict__ mask,
    float* __restrict__ u_att,
    float* __restrict__ u_last) {
  const int b = blockIdx.x;
  const int half = blockIdx.y;            // d-range [half*512, half*512+512)
  const int tid = threadIdx.x;
  const int lane = tid & 63;
  const int wave = tid >> 6;

  __shared__ float attn[SEQ];
  __shared__ float rbuf[4];
  __shared__ float part[3][64 * 9];       // padded stride 9

  float s0 = scores[(size_t)b * SEQ + tid];
  float s1 = scores[(size_t)b * SEQ + 256 + tid];
  if (mask[(size_t)b * SEQ + tid]) s0 = -1000000000.0f;
  if (mask[(size_t)b * SEQ + 256 + tid]) s1 = -1000000000.0f;

  float mx = fmaxf(s0, s1);
#pragma unroll
  for (int off = 1; off < 64; off <<= 1) mx = fmaxf(mx, __shfl_xor(mx, off));
  if (lane == 0) rbuf[wave] = mx;
  __syncthreads();
  mx = fmaxf(fmaxf(rbuf[0], rbuf[1]), fmaxf(rbuf[2], rbuf[3]));

  float p0 = expf(s0 - mx), p1 = expf(s1 - mx);
  float sm = p0 + p1;
#pragma unroll
  for (int off = 1; off < 64; off <<= 1) sm += __shfl_xor(sm, off);
  __syncthreads();
  if (lane == 0) rbuf[wave] = sm;
  __syncthreads();
  sm = rbuf[0] + rbuf[1] + rbuf[2] + rbuf[3];
  float inv = 1.0f / sm;
  attn[tid] = p0 * inv;
  attn[tid + 256] = p1 * inv;
  __syncthreads();

  // u_last: exact fp32 copy of X[:, 511, :] (this block's 512-d half)
  if (tid < 128) {
    ((f32x4*)u_last)[(size_t)b * 256 + half * 128 + tid] =
        ((const f32x4*)X)[((size_t)b * SEQ + (SEQ - 1)) * 256 + half * 128 + tid];
  }

  // u_att[b][d] = sum_s attn[s] * X[b][s][d]; block covers 512 d (64 groups of 8)
  const int col = tid & 63;            // 8-float group within the half
  const int sh = tid >> 6;             // s-range split: [sh*128, sh*128+128)
  const f32x4* Xp = (const f32x4*)X + (size_t)b * SEQ * 256 + half * 128 + col * 2;
  f32x4 a0 = {0.f, 0.f, 0.f, 0.f}, a1 = {0.f, 0.f, 0.f, 0.f};
  for (int s = sh * 128; s < sh * 128 + 128; s++) {
    float wgt = attn[s];
    a0 += wgt * Xp[(size_t)s * 256];
    a1 += wgt * Xp[(size_t)s * 256 + 1];
  }
  if (sh) {
#pragma unroll
    for (int j = 0; j < 4; j++) part[sh - 1][col * 9 + j] = a0[j];
#pragma unroll
    for (int j = 0; j < 4; j++) part[sh - 1][col * 9 + 4 + j] = a1[j];
  }
  __syncthreads();
  if (sh == 0) {
#pragma unroll
    for (int j = 0; j < 4; j++)
      a0[j] += part[0][col * 9 + j] + part[1][col * 9 + j] + part[2][col * 9 + j];
#pragma unroll
    for (int j = 0; j < 4; j++)
      a1[j] += part[0][col * 9 + 4 + j] + part[1][col * 9 + 4 + j] + part[2][col * 9 + 4 + j];
    f32x4* dst = (f32x4*)(u_att + (size_t)b * DIM + half * 512 + col * 8);
    dst[0] = a0;
    dst[1] = a1;
  }
}

// ---------- launcher ----------
extern "C" void kernel_launch(void* const* d_in, const int* in_sizes, int n_in,
                              void* d_out, int out_size, void* d_ws, size_t ws_size,
                              hipStream_t stream) {
  const float* X    = (const float*)d_in[0];   // [128][512][1024] fp32
  const int*   mask = (const int*)d_in[1];     // [128][512] int32 (bool)
  const float* W1   = (const float*)d_in[2];   // [1024][1024]
  const float* b1   = (const float*)d_in[3];   // [1024]
  const float* w2   = (const float*)d_in[4];   // [1024]

  float* out    = (float*)d_out;
  float* u_last = out;                          // [128][1024]
  float* u_att  = out + BATCH * DIM;            // [128][1024]

  char* ws = (char*)d_ws;
  unsigned short* W1t = (unsigned short*)ws;                        // 2 MB
  float* scores = (float*)(ws + (size_t)DIM * DIM * 2);             // 256 KB

  hipMemsetAsync(scores, 0, MROWS * sizeof(float), stream);
  hipLaunchKernelGGL(w1t_kernel, dim3(256), dim3(256), 0, stream, W1, W1t);
  hipLaunchKernelGGL(gemm_score_kernel, dim3(1024), dim3(512), 0, stream,
                     X, W1t, b1, w2, scores);
  hipLaunchKernelGGL(attn_uatt_kernel, dim3(128, 2), dim3(256), 0, stream,
                     X, scores, mask, u_att, u_last);
}

// Round 9
// 259.509 us; speedup vs baseline: 1.3661x; 1.0084x over previous
//
#include <hip/hip_runtime.h>
#include <hip/hip_bf16.h>
#include <cstdint>
#include <cstddef>

// Problem constants (fixed by the reference)
#define BATCH 128
#define SEQ   512
#define DIM   1024
#define MROWS (BATCH * SEQ)          // 65536
#define NT    32                     // K sub-tiles of 32 (DIM/32)

typedef short short8 __attribute__((ext_vector_type(8)));
typedef __bf16 bf16x8 __attribute__((ext_vector_type(8)));
typedef float f32x4 __attribute__((ext_vector_type(4)));

// ---------- MFMA wrapper: accept either builtin signature (short8 or bf16x8) ----------
template <typename VA> struct other_frag { using type = bf16x8; };
template <> struct other_frag<bf16x8> { using type = short8; };

template <typename VA>
__device__ __forceinline__ auto try_mfma(VA a, VA b, f32x4 c, int)
    -> decltype(__builtin_amdgcn_mfma_f32_16x16x32_bf16(a, b, c, 0, 0, 0)) {
  return __builtin_amdgcn_mfma_f32_16x16x32_bf16(a, b, c, 0, 0, 0);
}
template <typename VA>
__device__ __forceinline__ f32x4 try_mfma(VA a, VA b, f32x4 c, long) {
  using O = typename other_frag<VA>::type;
  O a2 = __builtin_bit_cast(O, a);
  O b2 = __builtin_bit_cast(O, b);
  return __builtin_amdgcn_mfma_f32_16x16x32_bf16(a2, b2, c, 0, 0, 0);
}
__device__ __forceinline__ f32x4 mfma_bf16(short8 a, short8 b, f32x4 c) {
  return try_mfma(a, b, c, 0);
}

// ---------- helpers ----------
__device__ __forceinline__ unsigned short f32_to_bf16(float f) {
  union { float f; uint32_t u; } v; v.f = f;
  uint32_t u = v.u;
  u += 0x7FFFu + ((u >> 16) & 1u);   // round-to-nearest-even
  return (unsigned short)(u >> 16);
}

// 8 x f32 -> 8 x bf16 (RNE)
__device__ __forceinline__ short8 cvt8(f32x4 a, f32x4 b) {
  bf16x8 o;
  o[0] = (__bf16)a[0]; o[1] = (__bf16)a[1]; o[2] = (__bf16)a[2]; o[3] = (__bf16)a[3];
  o[4] = (__bf16)b[0]; o[5] = (__bf16)b[1]; o[6] = (__bf16)b[2]; o[7] = (__bf16)b[3];
  return __builtin_bit_cast(short8, o);
}

__device__ __forceinline__ void gload_lds16(const void* g, void* l) {
  __builtin_amdgcn_global_load_lds(
      (__attribute__((address_space(1))) void*)g,
      (__attribute__((address_space(3))) void*)l,
      16, 0, 0);
}

__device__ __forceinline__ float fast_tanh(float x) {
  x = fminf(fmaxf(x, -15.0f), 15.0f);
  float e = __expf(2.0f * x);
  return (e - 1.0f) / (e + 1.0f);
}

// ---------- kernel 1: W1 (D x D) -> W1t bf16 (transposed, [e][d]) ----------
__global__ __launch_bounds__(256) void w1t_kernel(const float* __restrict__ W1,
                                                  unsigned short* __restrict__ W1t) {
  __shared__ float tile[64][65];
  int bx = blockIdx.x & 15;    // e-tile
  int by = blockIdx.x >> 4;    // d-tile
  int t = threadIdx.x;
  int c = t & 63, r0 = t >> 6;
#pragma unroll
  for (int i = 0; i < 16; i++) {
    int r = i * 4 + r0;
    tile[r][c] = W1[(size_t)(by * 64 + r) * DIM + bx * 64 + c];
  }
  __syncthreads();
#pragma unroll
  for (int i = 0; i < 16; i++) {
    int r = i * 4 + r0;
    W1t[(size_t)(bx * 64 + r) * DIM + by * 64 + c] = f32_to_bf16(tile[c][r]);
  }
}

// ---------- kernel 2: 256x256-tile pipelined GEMM (fp32 A direct) ----------
// C[m][e] = sum_d bf16(X[m][d]) * W1t[e][d]; scores[m] += sum_e tanh(C+b1[e])*w2[e]
//
// R8 skeleton unchanged (8 waves 2Mx4N, ring-3, counted vmcnt(6), barrier per
// K32-subtile, XCD-chunked grid).  ONE change vs R8: the A fp32 LDS layout is
// now an exact isomorph of the measured-0-conflict bf16 scheme.
//
// A per subtile = 32 KB, two PLANES of 16 KB (plane p holds floats
// [p*16, p*16+16) of each row's K32 window).  Within a plane: 256 logical
// rows x 16 floats; row-PAIRS pack into 128-B stored rows (sr = row>>1);
// 16-B chunk index js = ((row&1)*4 + q) ^ (sr&7), q = float-quad 0..3.
// Frag read (row = base+(lane&15), h = lane>>4): plane h>>1, quads
// (h&1)*2 + c, c = 0,1 -> js = ((row&1)*4 + (h&1)*2 + c) ^ (sr&7):
// per-16-lane-group constant K = (h&1)*2+c, the exact geometry of the
// verified-0 B reads (even/odd lane subsets each cover all 8 bank-quads).
//
// B bf16 [256 rows][32 k]: row-pairs in 128-B stored rows, chunk
// js = ((row&1)*4 + k16) ^ (srow&7)  (measured 0 conflicts, R2/R4).
// Staging writes LDS linearly (global_load_lds); global source applies the
// inverse permutation.
__global__ __launch_bounds__(512, 2) void gemm_score_kernel(
    const float* __restrict__ X,              // [MROWS][DIM] fp32
    const unsigned short* __restrict__ W1t,   // [DIM][DIM]  (e-major)
    const float* __restrict__ b1,
    const float* __restrict__ w2,
    float* __restrict__ scores) {             // [MROWS]
  __shared__ __align__(16) char lds[147456];  // A: [0,96K)  B: [96K,144K)

  const int tid = threadIdx.x;
  const int lane = tid & 63;
  const int w = tid >> 6;                     // wave 0..7
  const int wr = w >> 2, wc = w & 3;          // 2 x 4 wave grid

  // chunked XCD swizzle: 1024 blocks, 8 XCDs, n-fastest within each chunk
  const int bx = blockIdx.x;
  const int swz = (bx & 7) * 128 + (bx >> 3);
  const int m0 = (swz >> 2) * 256;
  const int n0 = (swz & 3) * 256;

  // ---- A staging sources: 4 chunks/thread, sc = i*512 + tid.
  // plane p = sc>>10; within-plane chunk cp = sc&1023: sr = cp>>3,
  // js = cp&7, j' = js ^ (sr&7), row = sr*2 + (j'>>2), q = j'&3.
  // global float offset = row*DIM + p*16 + q*4 (+ S*32 per subtile).
  const float* aSrc[4];
#pragma unroll
  for (int i = 0; i < 4; i++) {
    int sc = i * 512 + tid;
    int p = sc >> 10;
    int cp = sc & 1023;
    int sr = cp >> 3;
    int jp = (cp & 7) ^ (sr & 7);
    int row = sr * 2 + (jp >> 2);
    int q = jp & 3;
    aSrc[i] = X + (size_t)(m0 + row) * DIM + p * 16 + q * 4;
  }
  // ---- B staging sources: 2 chunks/thread, sc = i*512 + tid (16B bf16 chunks)
  const unsigned short* bSrc[2];
#pragma unroll
  for (int i = 0; i < 2; i++) {
    int sc = i * 512 + tid;
    int srow = sc >> 3;
    int j = (sc & 7) ^ (srow & 7);
    int row = srow * 2 + (j >> 2);
    bSrc[i] = W1t + (size_t)(n0 + row) * DIM + (j & 3) * 8;
  }

  // ---- fragment LDS byte offsets
  // A: within a 32KB subtile buffer; [mi][c], c = low/high f32x4 of the 8 floats
  int aOff[8][2];
#pragma unroll
  for (int mi = 0; mi < 8; mi++) {
    int row = wr * 128 + mi * 16 + (lane & 15);
    int sr = row >> 1;
    int h = lane >> 4;
    int plane = (h >> 1) * 16384;
#pragma unroll
    for (int c = 0; c < 2; c++) {
      int js = ((row & 1) * 4 + (h & 1) * 2 + c) ^ (sr & 7);
      aOff[mi][c] = plane + sr * 128 + js * 16;
    }
  }
  int bOff[4];                                // B: within a 16KB bf16 buffer
#pragma unroll
  for (int ni = 0; ni < 4; ni++) {
    int row = wc * 64 + ni * 16 + (lane & 15);
    int srow = row >> 1;
    int ic = ((row & 1) * 4 + (lane >> 4)) ^ (srow & 7);
    bOff[ni] = srow * 128 + ic * 16;
  }

  f32x4 acc[8][4];
#pragma unroll
  for (int mi = 0; mi < 8; mi++)
#pragma unroll
    for (int ni = 0; ni < 4; ni++)
      acc[mi][ni] = (f32x4){0.f, 0.f, 0.f, 0.f};

  short8 af[8], bfv[4];

#define STAGE(S) do {                                                   \
    const int bufA_ = ((S) % 3) * 32768;                                \
    const int bufB_ = 98304 + ((S) % 3) * 16384;                        \
    const int koF_ = (S) * 32;                                          \
    gload_lds16(aSrc[0] + koF_, lds + bufA_ + w * 1024);                \
    gload_lds16(aSrc[1] + koF_, lds + bufA_ + 8192 + w * 1024);         \
    gload_lds16(aSrc[2] + koF_, lds + bufA_ + 16384 + w * 1024);        \
    gload_lds16(aSrc[3] + koF_, lds + bufA_ + 24576 + w * 1024);        \
    gload_lds16(bSrc[0] + koF_, lds + bufB_ + w * 1024);                \
    gload_lds16(bSrc[1] + koF_, lds + bufB_ + 8192 + w * 1024);         \
  } while (0)

#define KITER(S, VMSTR) do {                                            \
    asm volatile("s_waitcnt vmcnt(" VMSTR ")" ::: "memory");            \
    __builtin_amdgcn_s_barrier();                                       \
    __builtin_amdgcn_sched_barrier(0);                                  \
    if ((S) + 2 < NT) STAGE((S) + 2);                                   \
    const char* bufA_ = lds + ((S) % 3) * 32768;                        \
    const char* bufB_ = lds + 98304 + ((S) % 3) * 16384;                \
    _Pragma("unroll")                                                   \
    for (int mi = 0; mi < 8; mi++) {                                    \
      f32x4 lo_ = *(const f32x4*)(bufA_ + aOff[mi][0]);                 \
      f32x4 hi_ = *(const f32x4*)(bufA_ + aOff[mi][1]);                 \
      af[mi] = cvt8(lo_, hi_);                                          \
    }                                                                   \
    _Pragma("unroll")                                                   \
    for (int ni = 0; ni < 4; ni++)                                      \
      bfv[ni] = *(const short8*)(bufB_ + bOff[ni]);                     \
    __builtin_amdgcn_s_setprio(1);                                      \
    _Pragma("unroll")                                                   \
    for (int mi = 0; mi < 8; mi++)                                      \
      _Pragma("unroll")                                                 \
      for (int ni = 0; ni < 4; ni++)                                    \
        acc[mi][ni] = mfma_bf16(af[mi], bfv[ni], acc[mi][ni]);          \
    __builtin_amdgcn_s_setprio(0);                                      \
  } while (0)

  // prologue: 2 sub-tiles in flight (12 wave-loads)
  STAGE(0); STAGE(1);

  for (int s = 0; s < NT - 1; ++s) KITER(s, "6");
  KITER(NT - 1, "0");

#undef STAGE
#undef KITER

  // epilogue: scores[row] += sum over this wave's 64 cols of tanh(c + b1) * w2
  const int cg = lane >> 4;   // row group: rows cg*4 + j
  const int cl = lane & 15;   // col within fragment
#pragma unroll
  for (int mi = 0; mi < 8; mi++) {
    float p0 = 0.f, p1 = 0.f, p2 = 0.f, p3 = 0.f;
#pragma unroll
    for (int ni = 0; ni < 4; ni++) {
      int col = n0 + wc * 64 + ni * 16 + cl;
      float w2v = w2[col];
      float b1v = b1[col];
      p0 += fast_tanh(acc[mi][ni][0] + b1v) * w2v;
      p1 += fast_tanh(acc[mi][ni][1] + b1v) * w2v;
      p2 += fast_tanh(acc[mi][ni][2] + b1v) * w2v;
      p3 += fast_tanh(acc[mi][ni][3] + b1v) * w2v;
    }
#pragma unroll
    for (int off = 1; off < 16; off <<= 1) {
      p0 += __shfl_xor(p0, off);
      p1 += __shfl_xor(p1, off);
      p2 += __shfl_xor(p2, off);
      p3 += __shfl_xor(p3, off);
    }
    if (cl == 0) {
      int row = m0 + wr * 128 + mi * 16 + cg * 4;
      atomicAdd(&scores[row + 0], p0);
      atomicAdd(&scores[row + 1], p1);
      atomicAdd(&scores[row + 2], p2);
      atomicAdd(&scores[row + 3], p3);
    }
  }
}

// ---------- kernel 3: masked softmax + u_att + u_last (fp32 X) ----------
__global__ __launch_bounds__(256) void attn_uatt_kernel(
    const float* __restrict__ X,
    const float* __restrict__ scores,
    const int* __restrict__ mask,
    float* __restrict__ u_att,
    float* __restrict__ u_last) {
  const int b = blockIdx.x;
  const int half = blockIdx.y;            // d-range [half*512, half*512+512)
  const int tid = threadIdx.x;
  const int lane = tid & 63;
  const int wave = tid >> 6;

  __shared__ float attn[SEQ];
  __shared__ float rbuf[4];
  __shared__ float part[3][64 * 9];       // padded stride 9

  float s0 = scores[(size_t)b * SEQ + tid];
  float s1 = scores[(size_t)b * SEQ + 256 + tid];
  if (mask[(size_t)b * SEQ + tid]) s0 = -1000000000.0f;
  if (mask[(size_t)b * SEQ + 256 + tid]) s1 = -1000000000.0f;

  float mx = fmaxf(s0, s1);
#pragma unroll
  for (int off = 1; off < 64; off <<= 1) mx = fmaxf(mx, __shfl_xor(mx, off));
  if (lane == 0) rbuf[wave] = mx;
  __syncthreads();
  mx = fmaxf(fmaxf(rbuf[0], rbuf[1]), fmaxf(rbuf[2], rbuf[3]));

  float p0 = expf(s0 - mx), p1 = expf(s1 - mx);
  float sm = p0 + p1;
#pragma unroll
  for (int off = 1; off < 64; off <<= 1) sm += __shfl_xor(sm, off);
  __syncthreads();
  if (lane == 0) rbuf[wave] = sm;
  __syncthreads();
  sm = rbuf[0] + rbuf[1] + rbuf[2] + rbuf[3];
  float inv = 1.0f / sm;
  attn[tid] = p0 * inv;
  attn[tid + 256] = p1 * inv;
  __syncthreads();

  // u_last: exact fp32 copy of X[:, 511, :] (this block's 512-d half)
  if (tid < 128) {
    ((f32x4*)u_last)[(size_t)b * 256 + half * 128 + tid] =
        ((const f32x4*)X)[((size_t)b * SEQ + (SEQ - 1)) * 256 + half * 128 + tid];
  }

  // u_att[b][d] = sum_s attn[s] * X[b][s][d]; block covers 512 d (64 groups of 8)
  const int col = tid & 63;            // 8-float group within the half
  const int sh = tid >> 6;             // s-range split: [sh*128, sh*128+128)
  const f32x4* Xp = (const f32x4*)X + (size_t)b * SEQ * 256 + half * 128 + col * 2;
  f32x4 a0 = {0.f, 0.f, 0.f, 0.f}, a1 = {0.f, 0.f, 0.f, 0.f};
  for (int s = sh * 128; s < sh * 128 + 128; s++) {
    float wgt = attn[s];
    a0 += wgt * Xp[(size_t)s * 256];
    a1 += wgt * Xp[(size_t)s * 256 + 1];
  }
  if (sh) {
#pragma unroll
    for (int j = 0; j < 4; j++) part[sh - 1][col * 9 + j] = a0[j];
#pragma unroll
    for (int j = 0; j < 4; j++) part[sh - 1][col * 9 + 4 + j] = a1[j];
  }
  __syncthreads();
  if (sh == 0) {
#pragma unroll
    for (int j = 0; j < 4; j++)
      a0[j] += part[0][col * 9 + j] + part[1][col * 9 + j] + part[2][col * 9 + j];
#pragma unroll
    for (int j = 0; j < 4; j++)
      a1[j] += part[0][col * 9 + 4 + j] + part[1][col * 9 + 4 + j] + part[2][col * 9 + 4 + j];
    f32x4* dst = (f32x4*)(u_att + (size_t)b * DIM + half * 512 + col * 8);
    dst[0] = a0;
    dst[1] = a1;
  }
}

// ---------- launcher ----------
extern "C" void kernel_launch(void* const* d_in, const int* in_sizes, int n_in,
                              void* d_out, int out_size, void* d_ws, size_t ws_size,
                              hipStream_t stream) {
  const float* X    = (const float*)d_in[0];   // [128][512][1024] fp32
  const int*   mask = (const int*)d_in[1];     // [128][512] int32 (bool)
  const float* W1   = (const float*)d_in[2];   // [1024][1024]
  const float* b1   = (const float*)d_in[3];   // [1024]
  const float* w2   = (const float*)d_in[4];   // [1024]

  float* out    = (float*)d_out;
  float* u_last = out;                          // [128][1024]
  float* u_att  = out + BATCH * DIM;            // [128][1024]

  char* ws = (char*)d_ws;
  unsigned short* W1t = (unsigned short*)ws;                        // 2 MB
  float* scores = (float*)(ws + (size_t)DIM * DIM * 2);             // 256 KB

  hipMemsetAsync(scores, 0, MROWS * sizeof(float), stream);
  hipLaunchKernelGGL(w1t_kernel, dim3(256), dim3(256), 0, stream, W1, W1t);
  hipLaunchKernelGGL(gemm_score_kernel, dim3(1024), dim3(512), 0, stream,
                     X, W1t, b1, w2, scores);
  hipLaunchKernelGGL(attn_uatt_kernel, dim3(128, 2), dim3(256), 0, stream,
                     X, scores, mask, u_att, u_last);
}

// Round 10
// 250.046 us; speedup vs baseline: 1.4178x; 1.0378x over previous
//
#include <hip/hip_runtime.h>
#include <hip/hip_bf16.h>
#include <cstdint>
#include <cstddef>

// Problem constants (fixed by the reference)
#define BATCH 128
#define SEQ   512
#define DIM   1024
#define MROWS (BATCH * SEQ)          // 65536
#define NT    32                     // K sub-tiles of 32 (DIM/32)

typedef short short8 __attribute__((ext_vector_type(8)));
typedef __bf16 bf16x8 __attribute__((ext_vector_type(8)));
typedef float f32x4 __attribute__((ext_vector_type(4)));

// ---------- MFMA wrapper: accept either builtin signature (short8 or bf16x8) ----------
template <typename VA> struct other_frag { using type = bf16x8; };
template <> struct other_frag<bf16x8> { using type = short8; };

template <typename VA>
__device__ __forceinline__ auto try_mfma(VA a, VA b, f32x4 c, int)
    -> decltype(__builtin_amdgcn_mfma_f32_16x16x32_bf16(a, b, c, 0, 0, 0)) {
  return __builtin_amdgcn_mfma_f32_16x16x32_bf16(a, b, c, 0, 0, 0);
}
template <typename VA>
__device__ __forceinline__ f32x4 try_mfma(VA a, VA b, f32x4 c, long) {
  using O = typename other_frag<VA>::type;
  O a2 = __builtin_bit_cast(O, a);
  O b2 = __builtin_bit_cast(O, b);
  return __builtin_amdgcn_mfma_f32_16x16x32_bf16(a2, b2, c, 0, 0, 0);
}
__device__ __forceinline__ f32x4 mfma_bf16(short8 a, short8 b, f32x4 c) {
  return try_mfma(a, b, c, 0);
}

// ---------- helpers ----------
__device__ __forceinline__ unsigned short f32_to_bf16(float f) {
  union { float f; uint32_t u; } v; v.f = f;
  uint32_t u = v.u;
  u += 0x7FFFu + ((u >> 16) & 1u);   // round-to-nearest-even
  return (unsigned short)(u >> 16);
}

// 8 x f32 -> 8 x bf16 (RNE)
__device__ __forceinline__ short8 cvt8(f32x4 a, f32x4 b) {
  bf16x8 o;
  o[0] = (__bf16)a[0]; o[1] = (__bf16)a[1]; o[2] = (__bf16)a[2]; o[3] = (__bf16)a[3];
  o[4] = (__bf16)b[0]; o[5] = (__bf16)b[1]; o[6] = (__bf16)b[2]; o[7] = (__bf16)b[3];
  return __builtin_bit_cast(short8, o);
}

__device__ __forceinline__ void gload_lds16(const void* g, void* l) {
  __builtin_amdgcn_global_load_lds(
      (__attribute__((address_space(1))) void*)g,
      (__attribute__((address_space(3))) void*)l,
      16, 0, 0);
}

__device__ __forceinline__ float fast_tanh(float x) {
  x = fminf(fmaxf(x, -15.0f), 15.0f);
  float e = __expf(2.0f * x);
  return (e - 1.0f) / (e + 1.0f);
}

// ---------- kernel 1: W1 (D x D) -> W1t bf16 (transposed, [e][d]) ----------
__global__ __launch_bounds__(256) void w1t_kernel(const float* __restrict__ W1,
                                                  unsigned short* __restrict__ W1t) {
  __shared__ float tile[64][65];
  int bx = blockIdx.x & 15;    // e-tile
  int by = blockIdx.x >> 4;    // d-tile
  int t = threadIdx.x;
  int c = t & 63, r0 = t >> 6;
#pragma unroll
  for (int i = 0; i < 16; i++) {
    int r = i * 4 + r0;
    tile[r][c] = W1[(size_t)(by * 64 + r) * DIM + bx * 64 + c];
  }
  __syncthreads();
#pragma unroll
  for (int i = 0; i < 16; i++) {
    int r = i * 4 + r0;
    W1t[(size_t)(bx * 64 + r) * DIM + by * 64 + c] = f32_to_bf16(tile[c][r]);
  }
}

// ---------- kernel 2: 256x256-tile pipelined GEMM (fp32 A direct) ----------
// C[m][e] = sum_d bf16(X[m][d]) * W1t[e][d]; scores[m] += sum_e tanh(C+b1[e])*w2[e]
//
// R9 skeleton unchanged (8 waves 2Mx4N, ring-3, counted vmcnt(6), barrier per
// K32-subtile, XCD-chunked grid).  ONE change vs R9: the A fp32 LDS granule
// permutation.
//
// HW model (fitted to R1..R9 counters, +4 cyc per conflicted b128 read):
// ds_read_b128 phases = stride-8 lane groups {p, p+8, ..., p+56}; conflict-
// free requires those 8 lanes to hit 8 distinct 16B granule-columns.
//
// A fp32 layout: one logical row (32 floats of the K32 window) = one 128-B
// stored row of 8 granules; granule js = q ^ (row&7) ^ ((row>>3)&7), q =
// float-quad 0..7.  Read (row = base+(lane&15), q = (lane>>4)*2 + c):
// stride-8 group -> js = (h*2+c) ^ p ^ E ^ tau with h*2^tau sweeping 0..7 ->
// distinct; consecutive-8 lanes -> distinct via the p term.  Safe under both
// phasing hypotheses (the measured-0 B-scheme also satisfies both).
//
// B bf16 [256 rows][32 k]: row-pairs in 128-B stored rows, chunk
// js = ((row&1)*4 + k16) ^ (srow&7)  (measured 0 conflicts, R2/R4).
// Staging writes LDS linearly (global_load_lds); global source applies the
// inverse permutation.
__global__ __launch_bounds__(512, 2) void gemm_score_kernel(
    const float* __restrict__ X,              // [MROWS][DIM] fp32
    const unsigned short* __restrict__ W1t,   // [DIM][DIM]  (e-major)
    const float* __restrict__ b1,
    const float* __restrict__ w2,
    float* __restrict__ scores) {             // [MROWS]
  __shared__ __align__(16) char lds[147456];  // A: [0,96K)  B: [96K,144K)

  const int tid = threadIdx.x;
  const int lane = tid & 63;
  const int w = tid >> 6;                     // wave 0..7
  const int wr = w >> 2, wc = w & 3;          // 2 x 4 wave grid

  // chunked XCD swizzle: 1024 blocks, 8 XCDs, n-fastest within each chunk
  const int bx = blockIdx.x;
  const int swz = (bx & 7) * 128 + (bx >> 3);
  const int m0 = (swz >> 2) * 256;
  const int n0 = (swz & 3) * 256;

  // ---- A staging sources: 4 chunks/thread, sc = i*512 + tid.
  // row = sc>>3, js = sc&7, q = js ^ (row&7) ^ ((row>>3)&7).
  // global float offset = row*DIM + q*4 (+ S*32 per subtile).
  const float* aSrc[4];
#pragma unroll
  for (int i = 0; i < 4; i++) {
    int sc = i * 512 + tid;
    int row = sc >> 3;
    int q = (sc & 7) ^ (row & 7) ^ ((row >> 3) & 7);
    aSrc[i] = X + (size_t)(m0 + row) * DIM + q * 4;
  }
  // ---- B staging sources: 2 chunks/thread, sc = i*512 + tid (16B bf16 chunks)
  const unsigned short* bSrc[2];
#pragma unroll
  for (int i = 0; i < 2; i++) {
    int sc = i * 512 + tid;
    int srow = sc >> 3;
    int j = (sc & 7) ^ (srow & 7);
    int row = srow * 2 + (j >> 2);
    bSrc[i] = W1t + (size_t)(n0 + row) * DIM + (j & 3) * 8;
  }

  // ---- fragment LDS byte offsets
  // A: within a 32KB subtile buffer; [mi][c], c = low/high f32x4 of the 8 floats
  int aOff[8][2];
#pragma unroll
  for (int mi = 0; mi < 8; mi++) {
    int row = wr * 128 + mi * 16 + (lane & 15);
    int m = (row & 7) ^ ((row >> 3) & 7);
#pragma unroll
    for (int c = 0; c < 2; c++) {
      int js = ((lane >> 4) * 2 + c) ^ m;
      aOff[mi][c] = row * 128 + js * 16;
    }
  }
  int bOff[4];                                // B: within a 16KB bf16 buffer
#pragma unroll
  for (int ni = 0; ni < 4; ni++) {
    int row = wc * 64 + ni * 16 + (lane & 15);
    int srow = row >> 1;
    int ic = ((row & 1) * 4 + (lane >> 4)) ^ (srow & 7);
    bOff[ni] = srow * 128 + ic * 16;
  }

  f32x4 acc[8][4];
#pragma unroll
  for (int mi = 0; mi < 8; mi++)
#pragma unroll
    for (int ni = 0; ni < 4; ni++)
      acc[mi][ni] = (f32x4){0.f, 0.f, 0.f, 0.f};

  short8 af[8], bfv[4];

#define STAGE(S) do {                                                   \
    const int bufA_ = ((S) % 3) * 32768;                                \
    const int bufB_ = 98304 + ((S) % 3) * 16384;                        \
    const int koF_ = (S) * 32;                                          \
    gload_lds16(aSrc[0] + koF_, lds + bufA_ + w * 1024);                \
    gload_lds16(aSrc[1] + koF_, lds + bufA_ + 8192 + w * 1024);         \
    gload_lds16(aSrc[2] + koF_, lds + bufA_ + 16384 + w * 1024);        \
    gload_lds16(aSrc[3] + koF_, lds + bufA_ + 24576 + w * 1024);        \
    gload_lds16(bSrc[0] + koF_, lds + bufB_ + w * 1024);                \
    gload_lds16(bSrc[1] + koF_, lds + bufB_ + 8192 + w * 1024);         \
  } while (0)

#define KITER(S, VMSTR) do {                                            \
    asm volatile("s_waitcnt vmcnt(" VMSTR ")" ::: "memory");            \
    __builtin_amdgcn_s_barrier();                                       \
    __builtin_amdgcn_sched_barrier(0);                                  \
    if ((S) + 2 < NT) STAGE((S) + 2);                                   \
    const char* bufA_ = lds + ((S) % 3) * 32768;                        \
    const char* bufB_ = lds + 98304 + ((S) % 3) * 16384;                \
    _Pragma("unroll")                                                   \
    for (int mi = 0; mi < 8; mi++) {                                    \
      f32x4 lo_ = *(const f32x4*)(bufA_ + aOff[mi][0]);                 \
      f32x4 hi_ = *(const f32x4*)(bufA_ + aOff[mi][1]);                 \
      af[mi] = cvt8(lo_, hi_);                                          \
    }                                                                   \
    _Pragma("unroll")                                                   \
    for (int ni = 0; ni < 4; ni++)                                      \
      bfv[ni] = *(const short8*)(bufB_ + bOff[ni]);                     \
    __builtin_amdgcn_s_setprio(1);                                      \
    _Pragma("unroll")                                                   \
    for (int mi = 0; mi < 8; mi++)                                      \
      _Pragma("unroll")                                                 \
      for (int ni = 0; ni < 4; ni++)                                    \
        acc[mi][ni] = mfma_bf16(af[mi], bfv[ni], acc[mi][ni]);          \
    __builtin_amdgcn_s_setprio(0);                                      \
  } while (0)

  // prologue: 2 sub-tiles in flight (12 wave-loads)
  STAGE(0); STAGE(1);

  for (int s = 0; s < NT - 1; ++s) KITER(s, "6");
  KITER(NT - 1, "0");

#undef STAGE
#undef KITER

  // epilogue: scores[row] += sum over this wave's 64 cols of tanh(c + b1) * w2
  const int cg = lane >> 4;   // row group: rows cg*4 + j
  const int cl = lane & 15;   // col within fragment
#pragma unroll
  for (int mi = 0; mi < 8; mi++) {
    float p0 = 0.f, p1 = 0.f, p2 = 0.f, p3 = 0.f;
#pragma unroll
    for (int ni = 0; ni < 4; ni++) {
      int col = n0 + wc * 64 + ni * 16 + cl;
      float w2v = w2[col];
      float b1v = b1[col];
      p0 += fast_tanh(acc[mi][ni][0] + b1v) * w2v;
      p1 += fast_tanh(acc[mi][ni][1] + b1v) * w2v;
      p2 += fast_tanh(acc[mi][ni][2] + b1v) * w2v;
      p3 += fast_tanh(acc[mi][ni][3] + b1v) * w2v;
    }
#pragma unroll
    for (int off = 1; off < 16; off <<= 1) {
      p0 += __shfl_xor(p0, off);
      p1 += __shfl_xor(p1, off);
      p2 += __shfl_xor(p2, off);
      p3 += __shfl_xor(p3, off);
    }
    if (cl == 0) {
      int row = m0 + wr * 128 + mi * 16 + cg * 4;
      atomicAdd(&scores[row + 0], p0);
      atomicAdd(&scores[row + 1], p1);
      atomicAdd(&scores[row + 2], p2);
      atomicAdd(&scores[row + 3], p3);
    }
  }
}

// ---------- kernel 3: masked softmax + u_att + u_last (fp32 X) ----------
__global__ __launch_bounds__(256) void attn_uatt_kernel(
    const float* __restrict__ X,
    const float* __restrict__ scores,
    const int* __restrict__ mask,
    float* __restrict__ u_att,
    float* __restrict__ u_last) {
  const int b = blockIdx.x;
  const int half = blockIdx.y;            // d-range [half*512, half*512+512)
  const int tid = threadIdx.x;
  const int lane = tid & 63;
  const int wave = tid >> 6;

  __shared__ float attn[SEQ];
  __shared__ float rbuf[4];
  __shared__ float part[3][64 * 9];       // padded stride 9

  float s0 = scores[(size_t)b * SEQ + tid];
  float s1 = scores[(size_t)b * SEQ + 256 + tid];
  if (mask[(size_t)b * SEQ + tid]) s0 = -1000000000.0f;
  if (mask[(size_t)b * SEQ + 256 + tid]) s1 = -1000000000.0f;

  float mx = fmaxf(s0, s1);
#pragma unroll
  for (int off = 1; off < 64; off <<= 1) mx = fmaxf(mx, __shfl_xor(mx, off));
  if (lane == 0) rbuf[wave] = mx;
  __syncthreads();
  mx = fmaxf(fmaxf(rbuf[0], rbuf[1]), fmaxf(rbuf[2], rbuf[3]));

  float p0 = expf(s0 - mx), p1 = expf(s1 - mx);
  float sm = p0 + p1;
#pragma unroll
  for (int off = 1; off < 64; off <<= 1) sm += __shfl_xor(sm, off);
  __syncthreads();
  if (lane == 0) rbuf[wave] = sm;
  __syncthreads();
  sm = rbuf[0] + rbuf[1] + rbuf[2] + rbuf[3];
  float inv = 1.0f / sm;
  attn[tid] = p0 * inv;
  attn[tid + 256] = p1 * inv;
  __syncthreads();

  // u_last: exact fp32 copy of X[:, 511, :] (this block's 512-d half)
  if (tid < 128) {
    ((f32x4*)u_last)[(size_t)b * 256 + half * 128 + tid] =
        ((const f32x4*)X)[((size_t)b * SEQ + (SEQ - 1)) * 256 + half * 128 + tid];
  }

  // u_att[b][d] = sum_s attn[s] * X[b][s][d]; block covers 512 d (64 groups of 8)
  const int col = tid & 63;            // 8-float group within the half
  const int sh = tid >> 6;             // s-range split: [sh*128, sh*128+128)
  const f32x4* Xp = (const f32x4*)X + (size_t)b * SEQ * 256 + half * 128 + col * 2;
  f32x4 a0 = {0.f, 0.f, 0.f, 0.f}, a1 = {0.f, 0.f, 0.f, 0.f};
  for (int s = sh * 128; s < sh * 128 + 128; s++) {
    float wgt = attn[s];
    a0 += wgt * Xp[(size_t)s * 256];
    a1 += wgt * Xp[(size_t)s * 256 + 1];
  }
  if (sh) {
#pragma unroll
    for (int j = 0; j < 4; j++) part[sh - 1][col * 9 + j] = a0[j];
#pragma unroll
    for (int j = 0; j < 4; j++) part[sh - 1][col * 9 + 4 + j] = a1[j];
  }
  __syncthreads();
  if (sh == 0) {
#pragma unroll
    for (int j = 0; j < 4; j++)
      a0[j] += part[0][col * 9 + j] + part[1][col * 9 + j] + part[2][col * 9 + j];
#pragma unroll
    for (int j = 0; j < 4; j++)
      a1[j] += part[0][col * 9 + 4 + j] + part[1][col * 9 + 4 + j] + part[2][col * 9 + 4 + j];
    f32x4* dst = (f32x4*)(u_att + (size_t)b * DIM + half * 512 + col * 8);
    dst[0] = a0;
    dst[1] = a1;
  }
}

// ---------- launcher ----------
extern "C" void kernel_launch(void* const* d_in, const int* in_sizes, int n_in,
                              void* d_out, int out_size, void* d_ws, size_t ws_size,
                              hipStream_t stream) {
  const float* X    = (const float*)d_in[0];   // [128][512][1024] fp32
  const int*   mask = (const int*)d_in[1];     // [128][512] int32 (bool)
  const float* W1   = (const float*)d_in[2];   // [1024][1024]
  const float* b1   = (const float*)d_in[3];   // [1024]
  const float* w2   = (const float*)d_in[4];   // [1024]

  float* out    = (float*)d_out;
  float* u_last = out;                          // [128][1024]
  float* u_att  = out + BATCH * DIM;            // [128][1024]

  char* ws = (char*)d_ws;
  unsigned short* W1t = (unsigned short*)ws;                        // 2 MB
  float* scores = (float*)(ws + (size_t)DIM * DIM * 2);             // 256 KB

  hipMemsetAsync(scores, 0, MROWS * sizeof(float), stream);
  hipLaunchKernelGGL(w1t_kernel, dim3(256), dim3(256), 0, stream, W1, W1t);
  hipLaunchKernelGGL(gemm_score_kernel, dim3(1024), dim3(512), 0, stream,
                     X, W1t, b1, w2, scores);
  hipLaunchKernelGGL(attn_uatt_kernel, dim3(128, 2), dim3(256), 0, stream,
                     X, scores, mask, u_att, u_last);
}